// Round 1
// 696.899 us; speedup vs baseline: 1.0084x; 1.0084x over previous
//
#include <hip/hip_runtime.h>

// ExtractSearchWindows: out[b,h,w,rr,tt] = (uint8)Q[b, h+off+ry+ty, w+off+rx+tx],
// Q = input padded by 6; stored as INT32.
//
// R8 theory: previous best (R7, 768 blocks x 24 iters) ran the kernel at
// ~2.6-2.8 TB/s of writes while the harness fill sustains 6.3 TB/s. Suspected
// cause: 2x __syncthreads per iteration -> compiler emits s_waitcnt vmcnt(0)
// before each s_barrier -> all waves drain the full store queue 24x in chip-wide
// lockstep, plus only 12 waves/CU. Fix: ONE group per block (grid=18432,
// 512 thr, 24 waves/CU), no loop -> stores never drained mid-kernel; offset
// table precomputed once into d_ws by a tiny prologue kernel (no per-block
// division math; table loads are coalesced dwordx4, L1/L2-hot, issued before
// the single barrier so its vmcnt drain covers only loads we need anyway).

#define KT 7
#define K2 49
#define MAX_SR 3
#define B_ 2
#define H_ 192
#define W_ 192
#define HW (H_ * W_)
#define PAD 6
#define NT 512
#define RMAX 5              // ceil(2401/512) quads per thread
#define PS 17               // patch row stride (13 rows x 16 cols used)
#define NGROUPS (B_ * H_ * W_ / 4)   // 18432 blocks, one group each
#define TABN (4 * NT * RMAX)         // 10240 entries >= 4*d_max = 9604

typedef int vint4 __attribute__((ext_vector_type(4)));

__device__ __forceinline__ int tab_entry(int jj, int cv, int offset, int d,
                                         int cvmagic) {
    if (jj >= 4 * d) jj = 4 * d - 1;            // clamp inactive tail
    int p_in = (jj >= d) + (jj >= 2 * d) + (jj >= 3 * d);
    int j  = jj - p_in * d;
    int rr = j / K2;                            // const divisor 49
    int tt = j - rr * K2;
    int ry = (rr * cvmagic) >> 16;              // rr / cv  (rr < 49)
    int rx = rr - ry * cv;
    int ty = tt / KT;                           // const divisor 7
    int tx = tt - ty * KT;
    // byte offset into int patch, incl. pixel-in-group column shift
    return 4 * ((offset + ry + ty) * PS + (offset + rx + tx) + p_in);
}

__global__ __launch_bounds__(256) void tab_kernel(
    int* __restrict__ tab, int cv, int offset, int d, int cvmagic)
{
    int jj = blockIdx.x * 256 + threadIdx.x;
    if (jj < TABN) tab[jj] = tab_entry(jj, cv, offset, d, cvmagic);
}

__global__ __launch_bounds__(NT, 6) void esw_kernel(
    const float* __restrict__ in, int* __restrict__ out,
    const int* __restrict__ tab,
    int cv, int offset, int d, int cvmagic)
{
    __shared__ int patch[13 * PS + 4];

    const int tid = threadIdx.x;
    const int g   = blockIdx.x;

    // Per-thread quad offset table: coalesced dwordx4 from L1/L2-hot tab,
    // issued before the barrier (fallback: compute inline if no workspace).
    vint4 f[RMAX];
    if (tab) {
        #pragma unroll
        for (int r = 0; r < RMAX; ++r)
            f[r] = *(const vint4*)(tab + 4 * (tid + NT * r));
    } else {
        #pragma unroll
        for (int r = 0; r < RMAX; ++r) {
            int j4 = 4 * (tid + NT * r);
            #pragma unroll
            for (int u = 0; u < 4; ++u)
                f[r][u] = tab_entry(j4 + u, cv, offset, d, cvmagic);
        }
    }

    const int pix0 = 4 * g;              // W divisible by 4 -> group in one row
    const int b   = pix0 / HW;           // const divisors -> magic mul
    const int rem = pix0 - b * HW;
    const int h   = rem / W_;
    const int w   = rem - h * W_;

    if (tid < 13 * 16) {                 // stage 13 rows x 16 cols (w-6..w+9)
        int dy = tid >> 4;
        int dx = tid & 15;
        int y = h + dy - PAD;
        int x = w + dx - PAD;
        int v = 0;
        if ((unsigned)y < (unsigned)H_ && (unsigned)x < (unsigned)W_)
            v = (int)in[b * HW + y * W_ + x];   // uint8 trunc; vals in [0,255)
        patch[dy * PS + dx] = v;
    }
    __syncthreads();                     // single barrier; drain covers only
                                         // tab/stage loads we need anyway

    int* op = out + (long long)g * (long long)(4 * d);  // 16B-aligned
    const char* pb = (const char*)patch;
    #pragma unroll
    for (int r = 0; r < RMAX; ++r) {
        int q = tid + NT * r;
        if (q < d) {                     // rounds 0..3 full; round 4 masked
            vint4 v;
            v.x = *(const int*)(pb + f[r].x);
            v.y = *(const int*)(pb + f[r].y);
            v.z = *(const int*)(pb + f[r].z);
            v.w = *(const int*)(pb + f[r].w);
            *(vint4*)(op + 4 * q) = v;
        }
    }
}

extern "C" void kernel_launch(void* const* d_in, const int* in_sizes, int n_in,
                              void* d_out, int out_size, void* d_ws, size_t ws_size,
                              hipStream_t stream) {
    const float* in = (const float*)d_in[0];
    int* out = (int*)d_out;

    // out_size = B*H*W * cv^2 * 49
    int cv2 = out_size / (B_ * H_ * W_ * K2);
    int cv = 1;
    while (cv * cv < cv2) ++cv;
    int offset = MAX_SR - (cv - 1) / 2;
    int d = cv2 * K2;
    int cvmagic = 65536 / cv + 1;

    int* tab = (ws_size >= (size_t)(TABN * sizeof(int))) ? (int*)d_ws : nullptr;
    if (tab)
        tab_kernel<<<(TABN + 255) / 256, 256, 0, stream>>>(tab, cv, offset, d,
                                                           cvmagic);
    esw_kernel<<<NGROUPS, NT, 0, stream>>>(in, out, tab, cv, offset, d, cvmagic);
}